// Round 1
// baseline (1414.576 us; speedup 1.0000x reference)
//
#include <hip/hip_runtime.h>
#include <stdint.h>

#define C 64  // C_IN == C_OUT == 64

// ---------------------------------------------------------------------------
// Kernel 1: h = leaky_relu(X @ W^T + b); write h to out[:, 0:64]; atomicMax
// monotonic-mapped keys into the agg region (interpreted as uint32).
// Layout: lane = output channel c. Each lane holds W[c][0..63] in registers.
// Each wave processes one row per iteration (row index is wave-uniform).
// ---------------------------------------------------------------------------
__global__ __launch_bounds__(256) void k_gemm_scatter(
    const float* __restrict__ feat, const float* __restrict__ W,
    const float* __restrict__ b, const int* __restrict__ idx,
    float* __restrict__ out, unsigned int* __restrict__ keys, int N)
{
    const int lane = threadIdx.x & 63;
    const int gw   = blockIdx.x * (blockDim.x >> 6) + (threadIdx.x >> 6);
    const int nw   = gridDim.x * (blockDim.x >> 6);

    // One-time: load this lane's W row (channel = lane) into 64 VGPRs.
    float w[C];
    const float4* Wrow = (const float4*)(W + (size_t)lane * C);
#pragma unroll
    for (int j = 0; j < C / 4; ++j) {
        float4 v = Wrow[j];
        w[4 * j + 0] = v.x; w[4 * j + 1] = v.y;
        w[4 * j + 2] = v.z; w[4 * j + 3] = v.w;
    }
    const float bias = b[lane];

    for (int n = gw; n < N; n += nw) {
        const float4* f4 = (const float4*)(feat + (size_t)n * C);
        float h0 = 0.f, h1 = 0.f, h2 = 0.f, h3 = 0.f;
#pragma unroll
        for (int j = 0; j < C / 4; ++j) {
            float4 v = f4[j];                 // all lanes same addr -> 1 line
            h0 = fmaf(v.x, w[4 * j + 0], h0);
            h1 = fmaf(v.y, w[4 * j + 1], h1);
            h2 = fmaf(v.z, w[4 * j + 2], h2);
            h3 = fmaf(v.w, w[4 * j + 3], h3);
        }
        float h = (h0 + h1) + (h2 + h3) + bias;
        h = fmaxf(h, 0.01f * h);              // leaky_relu

        out[(size_t)n * (2 * C) + lane] = h;  // coalesced 256B per wave

        // monotonic uint mapping: order-preserving, key 0 == "empty"
        unsigned int bits = __float_as_uint(h);
        unsigned int key  = (bits & 0x80000000u) ? ~bits : (bits | 0x80000000u);
        int seg = idx[n];                     // wave-uniform
        atomicMax(&keys[(size_t)seg * C + lane], key);
    }
}

// ---------------------------------------------------------------------------
// Kernel 2: decode keys in place -> float agg (key 0 => empty segment => 0.0)
// ---------------------------------------------------------------------------
__global__ __launch_bounds__(256) void k_decode(unsigned int* __restrict__ keys,
                                                int total)
{
    int i      = blockIdx.x * blockDim.x + threadIdx.x;
    int stride = gridDim.x * blockDim.x;
    for (; i < total; i += stride) {
        unsigned int k = keys[i];
        float f;
        if (k == 0u) {
            f = 0.0f;
        } else {
            unsigned int bits = (k & 0x80000000u) ? (k ^ 0x80000000u) : ~k;
            f = __uint_as_float(bits);
        }
        ((float*)keys)[i] = f;
    }
}

// ---------------------------------------------------------------------------
// Kernel 3: out[:, 64:128] = agg[idx[n]]  (float4 granularity)
// ---------------------------------------------------------------------------
__global__ __launch_bounds__(256) void k_gather(
    const float4* __restrict__ agg, const int* __restrict__ idx,
    float4* __restrict__ out4, int N)
{
    long long i      = (long long)blockIdx.x * blockDim.x + threadIdx.x;
    long long stride = (long long)gridDim.x * blockDim.x;
    long long total  = (long long)N * 16;   // 16 float4 per row (64 floats)
    for (; i < total; i += stride) {
        int n = (int)(i >> 4);
        int q = (int)(i & 15);
        int seg = idx[n];
        out4[(size_t)n * 32 + 16 + q] = agg[(size_t)seg * 16 + q];
    }
}

extern "C" void kernel_launch(void* const* d_in, const int* in_sizes, int n_in,
                              void* d_out, int out_size, void* d_ws, size_t ws_size,
                              hipStream_t stream)
{
    (void)n_in; (void)d_ws; (void)ws_size;
    const float* feat = (const float*)d_in[0];
    const float* W    = (const float*)d_in[1];
    const float* b    = (const float*)d_in[2];
    const int*   idx  = (const int*)d_in[3];
    float* out = (float*)d_out;

    const int N    = in_sizes[0] / C;                   // 1,600,000
    const int nseg = (out_size - N * 2 * C) / C;        // 100,000

    float* aggOut = out + (size_t)N * 2 * C;            // agg lives in d_out
    unsigned int* keys = (unsigned int*)aggOut;

    // init keys to 0 ("empty") every call — deterministic
    hipMemsetAsync(aggOut, 0, (size_t)nseg * C * sizeof(float), stream);

    k_gemm_scatter<<<2048, 256, 0, stream>>>(feat, W, b, idx, out, keys, N);
    k_decode<<<1024, 256, 0, stream>>>(keys, nseg * C);
    k_gather<<<4096, 256, 0, stream>>>((const float4*)aggOut, idx,
                                       (float4*)out, N);
}